// Round 14
// baseline (181.524 us; speedup 1.0000x reference)
//
#include <hip/hip_runtime.h>
#include <hip/hip_bf16.h>

constexpr int E     = 2048;   // edges
constexpr int NVARS = 512;    // variable nodes
constexpr int DMAX  = 20;     // max var degree supported (actual max ~14)
constexpr int TB    = 8;      // batch rows per tile
constexpr int NT    = 512;    // threads per block in main kernel
constexpr int NTILE = 16384 / TB;   // 2048 tiles
constexpr int GRID  = NTILE / 2;    // 1024 persistent blocks, 2 tiles each

// RNE float -> bf16 (HIGH 16 bits) — cold-path helper for the builder.
__device__ __forceinline__ unsigned bf16hi(float f) {
    const unsigned uu = __float_as_uint(f);
    return (uu + 0x7FFFu + ((uu >> 16) & 1u)) & 0xFFFF0000u;
}
// hot-path pack: one v_cvt_pk_bf16_f32 (RNE, same rounding as bf16hi)
__device__ __forceinline__ unsigned cvtpk(float lo, float hi) {
    unsigned r;
    asm("v_cvt_pk_bf16_f32 %0, %1, %2" : "=v"(r) : "v"(lo), "v"(hi));
    return r;
}
__device__ __forceinline__ float bl(unsigned q) { return __uint_as_float(q << 16); }
__device__ __forceinline__ float bh(unsigned q) { return __uint_as_float(q & 0xFFFF0000u); }

// ---------------------------------------------------------------------------
// kA: scan skip mask (4 MB) -> var(e) + fused skip weight. One nonzero per
// column => unique writer. grid (8, 32) x 256 threads, fully coalesced.
// ---------------------------------------------------------------------------
__global__ __launch_bounds__(256)
void k_vsrc(const float* __restrict__ skip_mask,
            const float* __restrict__ llr_w,
            unsigned short* __restrict__ vsrc,
            float* __restrict__ skw)
{
    const int col = blockIdx.x * 256 + threadIdx.x;
    const int v0  = blockIdx.y * (NVARS / 32);     // 16-row stripe
    for (int v = v0; v < v0 + NVARS / 32; ++v) {
        const float m = skip_mask[(size_t)v * E + col];
        if (m != 0.0f) {
            vsrc[col] = (unsigned short)v;
            skw [col] = m * llr_w[(size_t)v * E + col];
        }
    }
}

// ---------------------------------------------------------------------------
// kB: one wave per variable. Deterministic: every block derives identical
// deg[] from the same vsrc; bases are prefix sums over (deg,var)-order.
// Emits, per item (= group x chunk-of-4-outputs):
//   hdr[2*item]   = {skw(out0..3)}                      (float4)
//   hdr[2*item+1] = {cols01, cols23, woff, v | d<<16}   (uint4; col sentinel
//                                                        0xFFFF when o >= d)
//   wtc[woff + j] = uint4, component q = bf16(w(member j -> out q))<<16 | src
//   nitems[0]
// ---------------------------------------------------------------------------
__global__ __launch_bounds__(64)
void k_pervar(const unsigned short* __restrict__ vsrc,
              const float* __restrict__ skw,
              const float* __restrict__ odd_w,
              const float* __restrict__ u,
              const float* __restrict__ logits,
              uint4*  __restrict__ wtc,
              float4* __restrict__ hdr,
              int*    __restrict__ nitems)
{
    __shared__ unsigned short vs[E];       // 4 KB
    __shared__ int deg[NVARS];             // 2 KB
    __shared__ unsigned short mem[DMAX];
    __shared__ float zf[DMAX];
    __shared__ float sks[DMAX];

    const int v   = blockIdx.x;
    const int tid = threadIdx.x;           // 0..63 (one wave)

    for (int i = tid; i < E / 8; i += 64)
        ((uint4*)vs)[i] = ((const uint4*)vsrc)[i];
    for (int i = tid; i < NVARS; i += 64) deg[i] = 0;
    __syncthreads();
    for (int i = tid; i < E; i += 64) atomicAdd(&deg[vs[i]], 1);
    __syncthreads();

    const int dv = deg[v];

    // itot / item base / stream base via one pass + wave reductions.
    int itot = 0, ib = 0, wb = 0;
    for (int i = tid; i < NVARS; i += 64) {
        const int d2 = deg[i];
        if (!d2) continue;
        const int dc = (d2 < DMAX) ? d2 : DMAX;
        const int ic = (dc + 3) >> 2;
        itot += ic;
        if (dv > 0 && (d2 < dv || (d2 == dv && i < v))) { ib += ic; wb += dc * ic; }
    }
    #pragma unroll
    for (int o = 32; o; o >>= 1) {
        itot += __shfl_xor(itot, o);
        ib   += __shfl_xor(ib,   o);
        wb   += __shfl_xor(wb,   o);
    }
    if (v == 0 && tid == 0) nitems[0] = itot;
    if (!dv) return;
    const int de = (dv < DMAX) ? dv : DMAX;
    const int ic = (de + 3) >> 2;

    // member list: ballot compaction, ascending e (deterministic).
    int cnt = 0;
    for (int c = 0; c < E / 64; ++c) {
        const int e = c * 64 + tid;
        const bool m = ((int)vs[e] == v);
        const unsigned long long bal = __ballot(m);
        if (m) {
            const int pos = cnt + __popcll(bal & ((1ull << tid) - 1ull));
            if (pos < DMAX) mem[pos] = (unsigned short)e;
        }
        cnt += __popcll(bal);
    }
    __syncthreads();

    if (tid < de) {
        const int m = mem[tid];
        const float sig = 1.0f / (1.0f + __expf(-logits[m]));
        zf [tid] = (u[m] < sig) ? 1.0f : 0.0f;
        sks[tid] = skw[m];
    }
    __syncthreads();

    // headers
    if (tid < ic) {
        const int o0 = tid * 4;
        float s0 = 0, s1 = 0, s2 = 0, s3 = 0;
        unsigned c0 = 0xFFFFu, c1 = 0xFFFFu, c2 = 0xFFFFu, c3 = 0xFFFFu;
        if (o0 + 0 < de) { s0 = sks[o0 + 0]; c0 = mem[o0 + 0]; }
        if (o0 + 1 < de) { s1 = sks[o0 + 1]; c1 = mem[o0 + 1]; }
        if (o0 + 2 < de) { s2 = sks[o0 + 2]; c2 = mem[o0 + 2]; }
        if (o0 + 3 < de) { s3 = sks[o0 + 3]; c3 = mem[o0 + 3]; }
        hdr[2 * (ib + tid)]     = make_float4(s0, s1, s2, s3);
        hdr[2 * (ib + tid) + 1] = make_float4(
            __uint_as_float(c0 | (c1 << 16)),
            __uint_as_float(c2 | (c3 << 16)),
            __uint_as_float((unsigned)(wb + tid * de)),
            __uint_as_float((unsigned)v | ((unsigned)de << 16)));
    }

    // stream: entry (chunk k, member j)
    for (int idx = tid; idx < de * ic; idx += 64) {
        const int k = idx / de;
        const int j = idx - k * de;
        const int src = mem[j];
        unsigned g[4];
        #pragma unroll
        for (int q = 0; q < 4; ++q) {
            const int o = 4 * k + q;
            float ww = 0.0f;
            if (o < de && o != j)
                ww = odd_w[(size_t)src * E + mem[o]] * zf[j];
            g[q] = bf16hi(ww) | (unsigned)src;
        }
        wtc[wb + idx] = make_uint4(g[0], g[1], g[2], g[3]);
    }
}

// tanh(0.5*clip(s,-10,10)) = (e^c - 1)/(e^c + 1)
__device__ __forceinline__ float th(float s) {
    float c = fminf(fmaxf(s, -10.0f), 10.0f);
    float t = __expf(c);
    return (t - 1.0f) * __builtin_amdgcn_rcpf(t + 1.0f);
}

#define FMA8(gq, xvq)                                                         \
    {                                                                         \
        const float w0 = bh((gq).x), w1 = bh((gq).y);                         \
        const float w2 = bh((gq).z), w3 = bh((gq).w);                         \
        const float xf0 = bl((xvq).x), xf1 = bh((xvq).x);                     \
        const float xf2 = bl((xvq).y), xf3 = bh((xvq).y);                     \
        const float xf4 = bl((xvq).z), xf5 = bh((xvq).z);                     \
        const float xf6 = bl((xvq).w), xf7 = bh((xvq).w);                     \
        a[0][0] += w0 * xf0; a[0][1] += w0 * xf1;                             \
        a[0][2] += w0 * xf2; a[0][3] += w0 * xf3;                             \
        a[0][4] += w0 * xf4; a[0][5] += w0 * xf5;                             \
        a[0][6] += w0 * xf6; a[0][7] += w0 * xf7;                             \
        a[1][0] += w1 * xf0; a[1][1] += w1 * xf1;                             \
        a[1][2] += w1 * xf2; a[1][3] += w1 * xf3;                             \
        a[1][4] += w1 * xf4; a[1][5] += w1 * xf5;                             \
        a[1][6] += w1 * xf6; a[1][7] += w1 * xf7;                             \
        a[2][0] += w2 * xf0; a[2][1] += w2 * xf1;                             \
        a[2][2] += w2 * xf2; a[2][3] += w2 * xf3;                             \
        a[2][4] += w2 * xf4; a[2][5] += w2 * xf5;                             \
        a[2][6] += w2 * xf6; a[2][7] += w2 * xf7;                             \
        a[3][0] += w3 * xf0; a[3][1] += w3 * xf1;                             \
        a[3][2] += w3 * xf2; a[3][3] += w3 * xf3;                             \
        a[3][4] += w3 * xf4; a[3][5] += w3 * xf5;                             \
        a[3][6] += w3 * xf6; a[3][7] += w3 * xf7;                             \
    }

// ---------------------------------------------------------------------------
// Main fused kernel — persistent 2-tile blocks with register prefetch.
// Grid 1024; block handles tiles {bid, bid+1024}. After staging tile A to
// LDS, the next tile's 8 float4 x-loads are issued into registers (pinned
// via sched_barrier) so their HBM latency hides under tile A's gather+store.
// LDS 40 KB; __launch_bounds__(512,6) = 24 waves/CU (VGPR cap 85; kernel
// ~72-80 — NO spill expected; verify VGPR_Count/FETCH in post-mortem).
// ---------------------------------------------------------------------------
__global__ __launch_bounds__(NT, 6)
void fused_main(const float* __restrict__ x,          // [B, E]
                const float* __restrict__ llr,        // [B, NVARS]
                const uint4*  __restrict__ wtc,       // packed weight stream
                const float4* __restrict__ hdr,       // 2 x float4 per item
                const int*    __restrict__ nitems,
                float* __restrict__ out)
{
    __shared__ uint4 xs[E];        // stage: packed x; later: 4 output planes
    __shared__ uint4 ls[NVARS];

    const int t   = threadIdx.x;
    const int nit = nitems[0];

    float4 rx[8];
    {   // initial tile load (tile = blockIdx.x)
        const float4* xr = (const float4*)(x + (size_t)blockIdx.x * TB * E);
        #pragma unroll
        for (int i = 0; i < 8; ++i) rx[i] = xr[i * (E / 4) + t];
    }

    #pragma unroll 1
    for (int rep = 0; rep < 2; ++rep) {
        const int b0 = (blockIdx.x + rep * GRID) * TB;

        // llr just-in-time (8 coalesced scalars)
        const float* lr = llr + (size_t)b0 * NVARS;
        const float rl0 = lr[t],             rl1 = lr[NVARS + t];
        const float rl2 = lr[2 * NVARS + t], rl3 = lr[3 * NVARS + t];
        const float rl4 = lr[4 * NVARS + t], rl5 = lr[5 * NVARS + t];
        const float rl6 = lr[6 * NVARS + t], rl7 = lr[7 * NVARS + t];

        // stage regs -> LDS (bf16-packed, 8 rows per uint4)
        xs[4 * t + 0] = make_uint4(cvtpk(rx[0].x, rx[1].x), cvtpk(rx[2].x, rx[3].x),
                                   cvtpk(rx[4].x, rx[5].x), cvtpk(rx[6].x, rx[7].x));
        xs[4 * t + 1] = make_uint4(cvtpk(rx[0].y, rx[1].y), cvtpk(rx[2].y, rx[3].y),
                                   cvtpk(rx[4].y, rx[5].y), cvtpk(rx[6].y, rx[7].y));
        xs[4 * t + 2] = make_uint4(cvtpk(rx[0].z, rx[1].z), cvtpk(rx[2].z, rx[3].z),
                                   cvtpk(rx[4].z, rx[5].z), cvtpk(rx[6].z, rx[7].z));
        xs[4 * t + 3] = make_uint4(cvtpk(rx[0].w, rx[1].w), cvtpk(rx[2].w, rx[3].w),
                                   cvtpk(rx[4].w, rx[5].w), cvtpk(rx[6].w, rx[7].w));
        ls[t] = make_uint4(cvtpk(rl0, rl1), cvtpk(rl2, rl3),
                           cvtpk(rl4, rl5), cvtpk(rl6, rl7));
        __syncthreads();

        // prefetch next tile's x into registers; pin issue point here so the
        // loads fly during the gather+store phases below.
        if (rep == 0) {
            const float4* xr2 = (const float4*)(x + (size_t)(b0 + GRID * TB) * E);
            #pragma unroll
            for (int i = 0; i < 8; ++i) rx[i] = xr2[i * (E / 4) + t];
            __builtin_amdgcn_sched_barrier(0);
        }

        unsigned sst[2][4][4];
        unsigned scc[2][2];

        // ---------------- round 0 (unconditional: nit >= NT) ----------------
        {
            const float4 ha0 = hdr[2 * t];
            const uint4  hb0 = ((const uint4*)hdr)[2 * t + 1];
            const uint4* wp0 = wtc + hb0.z;
            const int v = hb0.w & 0xFFFF;
            const int d = hb0.w >> 16;

            const uint4 lvq = ls[v];
            const float lf0 = bl(lvq.x), lf1 = bh(lvq.x);
            const float lf2 = bl(lvq.y), lf3 = bh(lvq.y);
            const float lf4 = bl(lvq.z), lf5 = bh(lvq.z);
            const float lf6 = bl(lvq.w), lf7 = bh(lvq.w);

            float a[4][8];
            #pragma unroll
            for (int ii = 0; ii < 4; ++ii) {
                const float sk = (ii == 0) ? ha0.x : (ii == 1) ? ha0.y
                               : (ii == 2) ? ha0.z : ha0.w;
                a[ii][0] = sk * lf0; a[ii][1] = sk * lf1;
                a[ii][2] = sk * lf2; a[ii][3] = sk * lf3;
                a[ii][4] = sk * lf4; a[ii][5] = sk * lf5;
                a[ii][6] = sk * lf6; a[ii][7] = sk * lf7;
            }

            uint4 gc = wp0[0], gn = wp0[1];
            uint4 xc = xs[gc.x & 0x7FFu];
            for (int j = 0; j < d - 1; ++j) {
                const uint4 gf = wp0[j + 2];          // overread-safe
                const uint4 xn = xs[gn.x & 0x7FFu];
                FMA8(gc, xc);
                gc = gn; xc = xn; gn = gf;
            }
            FMA8(gc, xc);

            scc[0][0] = hb0.x;
            scc[0][1] = hb0.y;
            #pragma unroll
            for (int ii = 0; ii < 4; ++ii) {
                sst[0][ii][0] = cvtpk(th(a[ii][0]), th(a[ii][1]));
                sst[0][ii][1] = cvtpk(th(a[ii][2]), th(a[ii][3]));
                sst[0][ii][2] = cvtpk(th(a[ii][4]), th(a[ii][5]));
                sst[0][ii][3] = cvtpk(th(a[ii][6]), th(a[ii][7]));
            }
        }

        // ---------------- round 1 (guarded) ----------------
        scc[1][0] = 0xFFFFFFFFu;
        scc[1][1] = 0xFFFFFFFFu;
        if (NT + t < nit) {
            const int it = NT + t;
            const float4 ha1 = hdr[2 * it];
            const uint4  hb1 = ((const uint4*)hdr)[2 * it + 1];
            const uint4* wp1 = wtc + hb1.z;
            const int v = hb1.w & 0xFFFF;
            const int d = hb1.w >> 16;

            const uint4 lvq = ls[v];
            const float lf0 = bl(lvq.x), lf1 = bh(lvq.x);
            const float lf2 = bl(lvq.y), lf3 = bh(lvq.y);
            const float lf4 = bl(lvq.z), lf5 = bh(lvq.z);
            const float lf6 = bl(lvq.w), lf7 = bh(lvq.w);

            float a[4][8];
            #pragma unroll
            for (int ii = 0; ii < 4; ++ii) {
                const float sk = (ii == 0) ? ha1.x : (ii == 1) ? ha1.y
                               : (ii == 2) ? ha1.z : ha1.w;
                a[ii][0] = sk * lf0; a[ii][1] = sk * lf1;
                a[ii][2] = sk * lf2; a[ii][3] = sk * lf3;
                a[ii][4] = sk * lf4; a[ii][5] = sk * lf5;
                a[ii][6] = sk * lf6; a[ii][7] = sk * lf7;
            }

            uint4 gc = wp1[0], gn = wp1[1];
            uint4 xc = xs[gc.x & 0x7FFu];
            for (int j = 0; j < d - 1; ++j) {
                const uint4 gf = wp1[j + 2];
                const uint4 xn = xs[gn.x & 0x7FFu];
                FMA8(gc, xc);
                gc = gn; xc = xn; gn = gf;
            }
            FMA8(gc, xc);

            scc[1][0] = hb1.x;
            scc[1][1] = hb1.y;
            #pragma unroll
            for (int ii = 0; ii < 4; ++ii) {
                sst[1][ii][0] = cvtpk(th(a[ii][0]), th(a[ii][1]));
                sst[1][ii][1] = cvtpk(th(a[ii][2]), th(a[ii][3]));
                sst[1][ii][2] = cvtpk(th(a[ii][4]), th(a[ii][5]));
                sst[1][ii][3] = cvtpk(th(a[ii][6]), th(a[ii][7]));
            }
        }

        __syncthreads();                            // gathers done: xs free
        unsigned* osp = (unsigned*)xs;              // 4 planes x E (row pairs)
        #pragma unroll
        for (int r = 0; r < 2; ++r) {
            #pragma unroll
            for (int ii = 0; ii < 4; ++ii) {
                const unsigned c = (scc[r][ii >> 1] >> ((ii & 1) * 16)) & 0xFFFFu;
                if (c != 0xFFFFu) {
                    osp[0 * E + c] = sst[r][ii][0];
                    osp[1 * E + c] = sst[r][ii][1];
                    osp[2 * E + c] = sst[r][ii][2];
                    osp[3 * E + c] = sst[r][ii][3];
                }
            }
        }
        __syncthreads();

        // vectorized store: thread -> (row, lane); 8 float4 per thread
        {
            const int row = t >> 6, l = t & 63;
            const int p = row >> 1, hf = row & 1;
            float* orow = out + (size_t)(b0 + row) * E;
            const uint4* plane = (const uint4*)(osp + p * E);
            #pragma unroll
            for (int i = 0; i < 8; ++i) {
                const int q4 = i * 64 + l;              // 0..511
                const uint4 w4 = plane[q4];
                float4 o;
                if (hf == 0)
                    o = make_float4(bl(w4.x), bl(w4.y), bl(w4.z), bl(w4.w));
                else
                    o = make_float4(bh(w4.x), bh(w4.y), bh(w4.z), bh(w4.w));
                ((float4*)orow)[q4] = o;
            }
        }
        __syncthreads();                            // protect xs reuse (rep 1)
    }
}

extern "C" void kernel_launch(void* const* d_in, const int* in_sizes, int n_in,
                              void* d_out, int out_size, void* d_ws, size_t ws_size,
                              hipStream_t stream) {
    const float* x        = (const float*)d_in[0];  // [B, E]
    const float* llr      = (const float*)d_in[1];  // [B, NVARS]
    const float* u        = (const float*)d_in[2];  // [E]
    const float* odd_w    = (const float*)d_in[3];  // [E, E]
    const float* llr_w    = (const float*)d_in[4];  // [NVARS, E]
    const float* logits   = (const float*)d_in[5];  // [E]
    // d_in[6] (o2e_mask) not needed: structure derived from skip mask.
    const float* skip_msk = (const float*)d_in[7];  // [NVARS, E]
    float* out = (float*)d_out;

    // Workspace (~145 KB), 16B-aligned segments.
    char* wsb = (char*)d_ws;
    size_t off = 0;
    uint4*          wtc  = (uint4*)(wsb + off);          off += (size_t)6144 * 16;  // 98304
    float4*         hdr  = (float4*)(wsb + off);         off += (size_t)1024 * 32;  // 32768
    float*          skw  = (float*)(wsb + off);          off += (size_t)E * 4;      //  8192
    unsigned short* vsrc = (unsigned short*)(wsb + off); off += (size_t)E * 2;      //  4096
    int*            nit  = (int*)(wsb + off);            off += 16;

    k_vsrc  <<<dim3(E / 256, 32), dim3(256), 0, stream>>>(skip_msk, llr_w, vsrc, skw);
    k_pervar<<<dim3(NVARS),       dim3(64),  0, stream>>>(vsrc, skw, odd_w, u, logits,
                                                          wtc, hdr, nit);

    fused_main<<<dim3(GRID), dim3(NT), 0, stream>>>(x, llr, wtc, hdr, nit, out);
}

// Round 15
// 135.683 us; speedup vs baseline: 1.3379x; 1.3379x over previous
//
#include <hip/hip_runtime.h>
#include <hip/hip_bf16.h>

constexpr int E     = 2048;   // edges
constexpr int NVARS = 512;    // variable nodes
constexpr int DMAX  = 20;     // max var degree supported (actual max ~14)
constexpr int TB    = 8;      // batch rows per tile
constexpr int NT    = 512;    // threads per block in main kernel

// RNE float -> bf16 (HIGH 16 bits) — cold-path helper for the builder.
__device__ __forceinline__ unsigned bf16hi(float f) {
    const unsigned uu = __float_as_uint(f);
    return (uu + 0x7FFFu + ((uu >> 16) & 1u)) & 0xFFFF0000u;
}
// hot-path pack: one v_cvt_pk_bf16_f32 (RNE, same rounding as bf16hi)
__device__ __forceinline__ unsigned cvtpk(float lo, float hi) {
    unsigned r;
    asm("v_cvt_pk_bf16_f32 %0, %1, %2" : "=v"(r) : "v"(lo), "v"(hi));
    return r;
}
__device__ __forceinline__ float bl(unsigned q) { return __uint_as_float(q << 16); }
__device__ __forceinline__ float bh(unsigned q) { return __uint_as_float(q & 0xFFFF0000u); }

// ---------------------------------------------------------------------------
// kA: scan skip mask (4 MB) -> var(e) + fused skip weight. One nonzero per
// column => unique writer. grid (8, 32) x 256 threads, fully coalesced.
// ---------------------------------------------------------------------------
__global__ __launch_bounds__(256)
void k_vsrc(const float* __restrict__ skip_mask,
            const float* __restrict__ llr_w,
            unsigned short* __restrict__ vsrc,
            float* __restrict__ skw)
{
    const int col = blockIdx.x * 256 + threadIdx.x;
    const int v0  = blockIdx.y * (NVARS / 32);     // 16-row stripe
    for (int v = v0; v < v0 + NVARS / 32; ++v) {
        const float m = skip_mask[(size_t)v * E + col];
        if (m != 0.0f) {
            vsrc[col] = (unsigned short)v;
            skw [col] = m * llr_w[(size_t)v * E + col];
        }
    }
}

// ---------------------------------------------------------------------------
// kB: one wave per variable. Deterministic: every block derives identical
// deg[] from the same vsrc; bases are prefix sums over (deg,var)-order.
// Emits, per item (= group x chunk-of-4-outputs):
//   hdr[2*item]   = {skw(out0..3)}                      (float4)
//   hdr[2*item+1] = {cols01, cols23, woff, v | d<<16}   (uint4; col sentinel
//                                                        0xFFFF when o >= d)
//   wtc[woff + j] = uint4, component q = bf16(w(member j -> out q))<<16 | src
//   nitems[0]
// ---------------------------------------------------------------------------
__global__ __launch_bounds__(64)
void k_pervar(const unsigned short* __restrict__ vsrc,
              const float* __restrict__ skw,
              const float* __restrict__ odd_w,
              const float* __restrict__ u,
              const float* __restrict__ logits,
              uint4*  __restrict__ wtc,
              float4* __restrict__ hdr,
              int*    __restrict__ nitems)
{
    __shared__ unsigned short vs[E];       // 4 KB
    __shared__ int deg[NVARS];             // 2 KB
    __shared__ unsigned short mem[DMAX];
    __shared__ float zf[DMAX];
    __shared__ float sks[DMAX];

    const int v   = blockIdx.x;
    const int tid = threadIdx.x;           // 0..63 (one wave)

    for (int i = tid; i < E / 8; i += 64)
        ((uint4*)vs)[i] = ((const uint4*)vsrc)[i];
    for (int i = tid; i < NVARS; i += 64) deg[i] = 0;
    __syncthreads();
    for (int i = tid; i < E; i += 64) atomicAdd(&deg[vs[i]], 1);
    __syncthreads();

    const int dv = deg[v];

    // itot / item base / stream base via one pass + wave reductions.
    int itot = 0, ib = 0, wb = 0;
    for (int i = tid; i < NVARS; i += 64) {
        const int d2 = deg[i];
        if (!d2) continue;
        const int dc = (d2 < DMAX) ? d2 : DMAX;
        const int ic = (dc + 3) >> 2;
        itot += ic;
        if (dv > 0 && (d2 < dv || (d2 == dv && i < v))) { ib += ic; wb += dc * ic; }
    }
    #pragma unroll
    for (int o = 32; o; o >>= 1) {
        itot += __shfl_xor(itot, o);
        ib   += __shfl_xor(ib,   o);
        wb   += __shfl_xor(wb,   o);
    }
    if (v == 0 && tid == 0) nitems[0] = itot;
    if (!dv) return;
    const int de = (dv < DMAX) ? dv : DMAX;
    const int ic = (de + 3) >> 2;

    // member list: ballot compaction, ascending e (deterministic).
    int cnt = 0;
    for (int c = 0; c < E / 64; ++c) {
        const int e = c * 64 + tid;
        const bool m = ((int)vs[e] == v);
        const unsigned long long bal = __ballot(m);
        if (m) {
            const int pos = cnt + __popcll(bal & ((1ull << tid) - 1ull));
            if (pos < DMAX) mem[pos] = (unsigned short)e;
        }
        cnt += __popcll(bal);
    }
    __syncthreads();

    if (tid < de) {
        const int m = mem[tid];
        const float sig = 1.0f / (1.0f + __expf(-logits[m]));
        zf [tid] = (u[m] < sig) ? 1.0f : 0.0f;
        sks[tid] = skw[m];
    }
    __syncthreads();

    // headers
    if (tid < ic) {
        const int o0 = tid * 4;
        float s0 = 0, s1 = 0, s2 = 0, s3 = 0;
        unsigned c0 = 0xFFFFu, c1 = 0xFFFFu, c2 = 0xFFFFu, c3 = 0xFFFFu;
        if (o0 + 0 < de) { s0 = sks[o0 + 0]; c0 = mem[o0 + 0]; }
        if (o0 + 1 < de) { s1 = sks[o0 + 1]; c1 = mem[o0 + 1]; }
        if (o0 + 2 < de) { s2 = sks[o0 + 2]; c2 = mem[o0 + 2]; }
        if (o0 + 3 < de) { s3 = sks[o0 + 3]; c3 = mem[o0 + 3]; }
        hdr[2 * (ib + tid)]     = make_float4(s0, s1, s2, s3);
        hdr[2 * (ib + tid) + 1] = make_float4(
            __uint_as_float(c0 | (c1 << 16)),
            __uint_as_float(c2 | (c3 << 16)),
            __uint_as_float((unsigned)(wb + tid * de)),
            __uint_as_float((unsigned)v | ((unsigned)de << 16)));
    }

    // stream: entry (chunk k, member j)
    for (int idx = tid; idx < de * ic; idx += 64) {
        const int k = idx / de;
        const int j = idx - k * de;
        const int src = mem[j];
        unsigned g[4];
        #pragma unroll
        for (int q = 0; q < 4; ++q) {
            const int o = 4 * k + q;
            float ww = 0.0f;
            if (o < de && o != j)
                ww = odd_w[(size_t)src * E + mem[o]] * zf[j];
            g[q] = bf16hi(ww) | (unsigned)src;
        }
        wtc[wb + idx] = make_uint4(g[0], g[1], g[2], g[3]);
    }
}

// tanh(0.5*clip(s,-10,10)) = (e^c - 1)/(e^c + 1)
__device__ __forceinline__ float th(float s) {
    float c = fminf(fmaxf(s, -10.0f), 10.0f);
    float t = __expf(c);
    return (t - 1.0f) * __builtin_amdgcn_rcpf(t + 1.0f);
}

// 4-row FMA: g = uint4 weights (4 outputs, src in g.x low bits),
// xv = uint2 of 4 bf16 rows.
#define FMA4(gq, xv2)                                                         \
    {                                                                         \
        const float w0 = bh((gq).x), w1 = bh((gq).y);                         \
        const float w2 = bh((gq).z), w3 = bh((gq).w);                         \
        const float xf0 = bl((xv2).x), xf1 = bh((xv2).x);                     \
        const float xf2 = bl((xv2).y), xf3 = bh((xv2).y);                     \
        a[0][0] += w0 * xf0; a[0][1] += w0 * xf1;                             \
        a[0][2] += w0 * xf2; a[0][3] += w0 * xf3;                             \
        a[1][0] += w1 * xf0; a[1][1] += w1 * xf1;                             \
        a[1][2] += w1 * xf2; a[1][3] += w1 * xf3;                             \
        a[2][0] += w2 * xf0; a[2][1] += w2 * xf1;                             \
        a[2][2] += w2 * xf2; a[2][3] += w2 * xf3;                             \
        a[3][0] += w3 * xf0; a[3][1] += w3 * xf1;                             \
        a[3][2] += w3 * xf2; a[3][3] += w3 * xf3;                             \
    }

// Gather one item (4 outputs x 4 rows) from the given half-tile xs.
// HI = 0: use ls rows 0-3 (lv.x, lv.y); HI = 1: rows 4-7 (lv.z, lv.w).
template<int HI>
__device__ __forceinline__ void gather_item(
    const uint2* __restrict__ xsh, const uint4* __restrict__ lsq,
    const uint4* __restrict__ wtc, const float4 ha, const uint4 hb,
    unsigned st[4][2])
{
    const uint4* wp = wtc + hb.z;
    const int v = hb.w & 0xFFFF;
    const int d = hb.w >> 16;

    const uint4 lvq = lsq[v];
    const unsigned lp0 = HI ? lvq.z : lvq.x;     // rows 0,1 (or 4,5)
    const unsigned lp1 = HI ? lvq.w : lvq.y;     // rows 2,3 (or 6,7)
    const float lf0 = bl(lp0), lf1 = bh(lp0);
    const float lf2 = bl(lp1), lf3 = bh(lp1);

    float a[4][4];
    #pragma unroll
    for (int ii = 0; ii < 4; ++ii) {
        const float sk = (ii == 0) ? ha.x : (ii == 1) ? ha.y
                       : (ii == 2) ? ha.z : ha.w;
        a[ii][0] = sk * lf0; a[ii][1] = sk * lf1;
        a[ii][2] = sk * lf2; a[ii][3] = sk * lf3;
    }

    uint4 gc = wp[0], gn = wp[1];                // overread-safe (slack)
    uint2 xc = xsh[gc.x & 0x7FFu];
    for (int j = 0; j < d - 1; ++j) {
        const uint4 gf = wp[j + 2];
        const uint2 xn = xsh[gn.x & 0x7FFu];
        FMA4(gc, xc);
        gc = gn; xc = xn; gn = gf;
    }
    FMA4(gc, xc);

    #pragma unroll
    for (int ii = 0; ii < 4; ++ii) {
        st[ii][0] = cvtpk(th(a[ii][0]), th(a[ii][1]));
        st[ii][1] = cvtpk(th(a[ii][2]), th(a[ii][3]));
    }
}

// ---------------------------------------------------------------------------
// Main fused kernel — half-tile pipeline. Rows 0-3 (A) and 4-7 (B) are
// processed as separate gather/scatter/store phases so HBM bursts interleave
// with compute: B's x-loads issue during gatherA; storeA's async stores
// overlap gatherB. Per-item acc = 16 f32 -> peak ~77 VGPR under the 85 cap
// of __launch_bounds__(512,6). LDS = xsA 16 + xsB 16 + ls 8 = 40 KB.
// ---------------------------------------------------------------------------
__global__ __launch_bounds__(NT, 6)
void fused_main(const float* __restrict__ x,          // [B, E]
                const float* __restrict__ llr,        // [B, NVARS]
                const uint4*  __restrict__ wtc,       // packed weight stream
                const float4* __restrict__ hdr,       // 2 x float4 per item
                const int*    __restrict__ nitems,
                float* __restrict__ out)
{
    __shared__ uint2 xsA[E];       // rows 0-3 bf16; later: out planes 0,1
    __shared__ uint2 xsB[E];       // rows 4-7 bf16; later: out planes 2,3
    __shared__ uint4 ls[NVARS];    // llr rows 0-7 bf16

    const int b0 = blockIdx.x * TB;
    const int t  = threadIdx.x;
    const int nit = nitems[0];

    // ---- load rows 0-3 + llr; prefetch item-0 header ----
    const float4* xr = (const float4*)(x + (size_t)b0 * E);
    const float4 r0 = xr[0 * (E / 4) + t];
    const float4 r1 = xr[1 * (E / 4) + t];
    const float4 r2 = xr[2 * (E / 4) + t];
    const float4 r3 = xr[3 * (E / 4) + t];
    const float* lr = llr + (size_t)b0 * NVARS;
    const float l0 = lr[t],             l1 = lr[NVARS + t];
    const float l2 = lr[2 * NVARS + t], l3 = lr[3 * NVARS + t];
    const float l4 = lr[4 * NVARS + t], l5 = lr[5 * NVARS + t];
    const float l6 = lr[6 * NVARS + t], l7 = lr[7 * NVARS + t];

    const float4 ha0 = hdr[2 * t];
    const uint4  hb0 = ((const uint4*)hdr)[2 * t + 1];

    xsA[4 * t + 0] = make_uint2(cvtpk(r0.x, r1.x), cvtpk(r2.x, r3.x));
    xsA[4 * t + 1] = make_uint2(cvtpk(r0.y, r1.y), cvtpk(r2.y, r3.y));
    xsA[4 * t + 2] = make_uint2(cvtpk(r0.z, r1.z), cvtpk(r2.z, r3.z));
    xsA[4 * t + 3] = make_uint2(cvtpk(r0.w, r1.w), cvtpk(r2.w, r3.w));
    ls[t] = make_uint4(cvtpk(l0, l1), cvtpk(l2, l3),
                       cvtpk(l4, l5), cvtpk(l6, l7));
    __syncthreads();

    unsigned st0[4][2], st1[4][2];
    unsigned scc0x = hb0.x, scc0y = hb0.y;
    unsigned scc1x = 0xFFFFFFFFu, scc1y = 0xFFFFFFFFu;

    // ---- gather A round 0 ----
    gather_item<0>(xsA, ls, wtc, ha0, hb0, st0);

    // ---- issue rows 4-7 loads (16 VGPR, held through round 1) ----
    const float4 s4 = xr[4 * (E / 4) + t];
    const float4 s5 = xr[5 * (E / 4) + t];
    const float4 s6 = xr[6 * (E / 4) + t];
    const float4 s7 = xr[7 * (E / 4) + t];
    __builtin_amdgcn_sched_barrier(0);

    // ---- gather A round 1 (guarded) ----
    const bool valid1 = (NT + t < nit);
    float4 ha1; uint4 hb1;
    if (valid1) {
        ha1 = hdr[2 * (NT + t)];
        hb1 = ((const uint4*)hdr)[2 * (NT + t) + 1];
        scc1x = hb1.x; scc1y = hb1.y;
        gather_item<0>(xsA, ls, wtc, ha1, hb1, st1);
    }

    __syncthreads();                     // A gathers done: xsA reusable

    // ---- stage B; scatter A into ospA (= xsA) ----
    xsB[4 * t + 0] = make_uint2(cvtpk(s4.x, s5.x), cvtpk(s6.x, s7.x));
    xsB[4 * t + 1] = make_uint2(cvtpk(s4.y, s5.y), cvtpk(s6.y, s7.y));
    xsB[4 * t + 2] = make_uint2(cvtpk(s4.z, s5.z), cvtpk(s6.z, s7.z));
    xsB[4 * t + 3] = make_uint2(cvtpk(s4.w, s5.w), cvtpk(s6.w, s7.w));

    unsigned* ospA = (unsigned*)xsA;     // plane 0: rows 0,1; plane 1: rows 2,3
    #pragma unroll
    for (int ii = 0; ii < 4; ++ii) {
        const unsigned c = ((ii < 2 ? scc0x : scc0y) >> ((ii & 1) * 16)) & 0xFFFFu;
        if (c != 0xFFFFu) { ospA[c] = st0[ii][0]; ospA[E + c] = st0[ii][1]; }
    }
    #pragma unroll
    for (int ii = 0; ii < 4; ++ii) {
        const unsigned c = ((ii < 2 ? scc1x : scc1y) >> ((ii & 1) * 16)) & 0xFFFFu;
        if (c != 0xFFFFu) { ospA[c] = st1[ii][0]; ospA[E + c] = st1[ii][1]; }
    }
    __syncthreads();                     // ospA + xsB ready

    // ---- store A (async; overlaps gather B below) ----
    {
        const int row = t >> 7, l = t & 127;       // 4 rows x 128 threads
        const int p = row >> 1, hf = row & 1;
        float* orow = out + (size_t)(b0 + row) * E;
        const uint4* pl = (const uint4*)(ospA + p * E);
        #pragma unroll
        for (int i = 0; i < 4; ++i) {
            const int q4 = i * 128 + l;            // 0..511
            const uint4 w4 = pl[q4];
            float4 o;
            if (hf == 0) o = make_float4(bl(w4.x), bl(w4.y), bl(w4.z), bl(w4.w));
            else         o = make_float4(bh(w4.x), bh(w4.y), bh(w4.z), bh(w4.w));
            ((float4*)orow)[q4] = o;
        }
    }

    // ---- gather B (rows 4-7; headers re-read, L1-hot) ----
    gather_item<1>(xsB, ls, wtc, ha0, hb0, st0);
    if (valid1)
        gather_item<1>(xsB, ls, wtc, ha1, hb1, st1);

    __syncthreads();                     // B gathers done: xsB reusable

    unsigned* ospB = (unsigned*)xsB;     // plane 0: rows 4,5; plane 1: rows 6,7
    #pragma unroll
    for (int ii = 0; ii < 4; ++ii) {
        const unsigned c = ((ii < 2 ? scc0x : scc0y) >> ((ii & 1) * 16)) & 0xFFFFu;
        if (c != 0xFFFFu) { ospB[c] = st0[ii][0]; ospB[E + c] = st0[ii][1]; }
    }
    #pragma unroll
    for (int ii = 0; ii < 4; ++ii) {
        const unsigned c = ((ii < 2 ? scc1x : scc1y) >> ((ii & 1) * 16)) & 0xFFFFu;
        if (c != 0xFFFFu) { ospB[c] = st1[ii][0]; ospB[E + c] = st1[ii][1]; }
    }
    __syncthreads();

    // ---- store B ----
    {
        const int row = t >> 7, l = t & 127;
        const int p = row >> 1, hf = row & 1;
        float* orow = out + (size_t)(b0 + 4 + row) * E;
        const uint4* pl = (const uint4*)(ospB + p * E);
        #pragma unroll
        for (int i = 0; i < 4; ++i) {
            const int q4 = i * 128 + l;
            const uint4 w4 = pl[q4];
            float4 o;
            if (hf == 0) o = make_float4(bl(w4.x), bl(w4.y), bl(w4.z), bl(w4.w));
            else         o = make_float4(bh(w4.x), bh(w4.y), bh(w4.z), bh(w4.w));
            ((float4*)orow)[q4] = o;
        }
    }
}

extern "C" void kernel_launch(void* const* d_in, const int* in_sizes, int n_in,
                              void* d_out, int out_size, void* d_ws, size_t ws_size,
                              hipStream_t stream) {
    const float* x        = (const float*)d_in[0];  // [B, E]
    const float* llr      = (const float*)d_in[1];  // [B, NVARS]
    const float* u        = (const float*)d_in[2];  // [E]
    const float* odd_w    = (const float*)d_in[3];  // [E, E]
    const float* llr_w    = (const float*)d_in[4];  // [NVARS, E]
    const float* logits   = (const float*)d_in[5];  // [E]
    // d_in[6] (o2e_mask) not needed: structure derived from skip mask.
    const float* skip_msk = (const float*)d_in[7];  // [NVARS, E]
    float* out = (float*)d_out;

    const int B = in_sizes[0] / E;                  // 16384

    // Workspace (~145 KB), 16B-aligned segments.
    char* wsb = (char*)d_ws;
    size_t off = 0;
    uint4*          wtc  = (uint4*)(wsb + off);          off += (size_t)6144 * 16;  // 98304
    float4*         hdr  = (float4*)(wsb + off);         off += (size_t)1024 * 32;  // 32768
    float*          skw  = (float*)(wsb + off);          off += (size_t)E * 4;      //  8192
    unsigned short* vsrc = (unsigned short*)(wsb + off); off += (size_t)E * 2;      //  4096
    int*            nit  = (int*)(wsb + off);            off += 16;

    k_vsrc  <<<dim3(E / 256, 32), dim3(256), 0, stream>>>(skip_msk, llr_w, vsrc, skw);
    k_pervar<<<dim3(NVARS),       dim3(64),  0, stream>>>(vsrc, skw, odd_w, u, logits,
                                                          wtc, hdr, nit);

    fused_main<<<dim3(B / TB), dim3(NT), 0, stream>>>(x, llr, wtc, hdr, nit, out);
}

// Round 16
// 91.586 us; speedup vs baseline: 1.9820x; 1.4815x over previous
//
#include <hip/hip_runtime.h>
#include <hip/hip_bf16.h>

constexpr int E     = 2048;   // edges
constexpr int NVARS = 512;    // variable nodes
constexpr int DMAX  = 20;     // max var degree supported (actual max ~14)
constexpr int TB    = 8;      // batch rows per block in main kernel
constexpr int NT    = 512;    // threads per block in main kernel

// RNE float -> bf16 (HIGH 16 bits) — cold-path helper for the builder.
__device__ __forceinline__ unsigned bf16hi(float f) {
    const unsigned uu = __float_as_uint(f);
    return (uu + 0x7FFFu + ((uu >> 16) & 1u)) & 0xFFFF0000u;
}
// hot-path pack: one v_cvt_pk_bf16_f32 (RNE, same rounding as bf16hi)
__device__ __forceinline__ unsigned cvtpk(float lo, float hi) {
    unsigned r;
    asm("v_cvt_pk_bf16_f32 %0, %1, %2" : "=v"(r) : "v"(lo), "v"(hi));
    return r;
}
__device__ __forceinline__ float bl(unsigned q) { return __uint_as_float(q << 16); }
__device__ __forceinline__ float bh(unsigned q) { return __uint_as_float(q & 0xFFFF0000u); }

// ---------------------------------------------------------------------------
// kA: scan skip mask (4 MB) -> var(e) + fused skip weight. One nonzero per
// column => unique writer. grid (8, 32) x 256 threads, fully coalesced.
// ---------------------------------------------------------------------------
__global__ __launch_bounds__(256)
void k_vsrc(const float* __restrict__ skip_mask,
            const float* __restrict__ llr_w,
            unsigned short* __restrict__ vsrc,
            float* __restrict__ skw)
{
    const int col = blockIdx.x * 256 + threadIdx.x;
    const int v0  = blockIdx.y * (NVARS / 32);     // 16-row stripe
    for (int v = v0; v < v0 + NVARS / 32; ++v) {
        const float m = skip_mask[(size_t)v * E + col];
        if (m != 0.0f) {
            vsrc[col] = (unsigned short)v;
            skw [col] = m * llr_w[(size_t)v * E + col];
        }
    }
}

// ---------------------------------------------------------------------------
// kB: one wave per variable. Deterministic: every block derives identical
// deg[] from the same vsrc; bases are prefix sums over (deg,var)-order.
// Emits, per item (= group x chunk-of-4-outputs):
//   hdr[2*item]   = {skw(out0..3)}                      (float4)
//   hdr[2*item+1] = {cols01, cols23, woff, v | d<<16}   (uint4; col sentinel
//                                                        0xFFFF when o >= d)
//   wtc[woff + j] = uint4, component q = bf16(w(member j -> out q))<<16 | src
//   nitems[0]
// ---------------------------------------------------------------------------
__global__ __launch_bounds__(64)
void k_pervar(const unsigned short* __restrict__ vsrc,
              const float* __restrict__ skw,
              const float* __restrict__ odd_w,
              const float* __restrict__ u,
              const float* __restrict__ logits,
              uint4*  __restrict__ wtc,
              float4* __restrict__ hdr,
              int*    __restrict__ nitems)
{
    __shared__ unsigned short vs[E];       // 4 KB
    __shared__ int deg[NVARS];             // 2 KB
    __shared__ unsigned short mem[DMAX];
    __shared__ float zf[DMAX];
    __shared__ float sks[DMAX];

    const int v   = blockIdx.x;
    const int tid = threadIdx.x;           // 0..63 (one wave)

    for (int i = tid; i < E / 8; i += 64)
        ((uint4*)vs)[i] = ((const uint4*)vsrc)[i];
    for (int i = tid; i < NVARS; i += 64) deg[i] = 0;
    __syncthreads();
    for (int i = tid; i < E; i += 64) atomicAdd(&deg[vs[i]], 1);
    __syncthreads();

    const int dv = deg[v];

    // itot / item base / stream base via one pass + wave reductions.
    int itot = 0, ib = 0, wb = 0;
    for (int i = tid; i < NVARS; i += 64) {
        const int d2 = deg[i];
        if (!d2) continue;
        const int dc = (d2 < DMAX) ? d2 : DMAX;
        const int ic = (dc + 3) >> 2;
        itot += ic;
        if (dv > 0 && (d2 < dv || (d2 == dv && i < v))) { ib += ic; wb += dc * ic; }
    }
    #pragma unroll
    for (int o = 32; o; o >>= 1) {
        itot += __shfl_xor(itot, o);
        ib   += __shfl_xor(ib,   o);
        wb   += __shfl_xor(wb,   o);
    }
    if (v == 0 && tid == 0) nitems[0] = itot;
    if (!dv) return;
    const int de = (dv < DMAX) ? dv : DMAX;
    const int ic = (de + 3) >> 2;

    // member list: ballot compaction, ascending e (deterministic).
    int cnt = 0;
    for (int c = 0; c < E / 64; ++c) {
        const int e = c * 64 + tid;
        const bool m = ((int)vs[e] == v);
        const unsigned long long bal = __ballot(m);
        if (m) {
            const int pos = cnt + __popcll(bal & ((1ull << tid) - 1ull));
            if (pos < DMAX) mem[pos] = (unsigned short)e;
        }
        cnt += __popcll(bal);
    }
    __syncthreads();

    if (tid < de) {
        const int m = mem[tid];
        const float sig = 1.0f / (1.0f + __expf(-logits[m]));
        zf [tid] = (u[m] < sig) ? 1.0f : 0.0f;
        sks[tid] = skw[m];
    }
    __syncthreads();

    // headers
    if (tid < ic) {
        const int o0 = tid * 4;
        float s0 = 0, s1 = 0, s2 = 0, s3 = 0;
        unsigned c0 = 0xFFFFu, c1 = 0xFFFFu, c2 = 0xFFFFu, c3 = 0xFFFFu;
        if (o0 + 0 < de) { s0 = sks[o0 + 0]; c0 = mem[o0 + 0]; }
        if (o0 + 1 < de) { s1 = sks[o0 + 1]; c1 = mem[o0 + 1]; }
        if (o0 + 2 < de) { s2 = sks[o0 + 2]; c2 = mem[o0 + 2]; }
        if (o0 + 3 < de) { s3 = sks[o0 + 3]; c3 = mem[o0 + 3]; }
        hdr[2 * (ib + tid)]     = make_float4(s0, s1, s2, s3);
        hdr[2 * (ib + tid) + 1] = make_float4(
            __uint_as_float(c0 | (c1 << 16)),
            __uint_as_float(c2 | (c3 << 16)),
            __uint_as_float((unsigned)(wb + tid * de)),
            __uint_as_float((unsigned)v | ((unsigned)de << 16)));
    }

    // stream: entry (chunk k, member j)
    for (int idx = tid; idx < de * ic; idx += 64) {
        const int k = idx / de;
        const int j = idx - k * de;
        const int src = mem[j];
        unsigned g[4];
        #pragma unroll
        for (int q = 0; q < 4; ++q) {
            const int o = 4 * k + q;
            float ww = 0.0f;
            if (o < de && o != j)
                ww = odd_w[(size_t)src * E + mem[o]] * zf[j];
            g[q] = bf16hi(ww) | (unsigned)src;
        }
        wtc[wb + idx] = make_uint4(g[0], g[1], g[2], g[3]);
    }
}

// tanh(0.5*clip(s,-10,10)) = (e^c - 1)/(e^c + 1)
__device__ __forceinline__ float th(float s) {
    float c = fminf(fmaxf(s, -10.0f), 10.0f);
    float t = __expf(c);
    return (t - 1.0f) * __builtin_amdgcn_rcpf(t + 1.0f);
}

// ---------------------------------------------------------------------------
// Main fused kernel, group-structured. One item = (var-group, chunk of <=4
// outputs). Per member j: ONE contiguous uint4 stream load (weights + src)
// + ONE ds_read_b128 serving 4 outputs x 8 rows. Outputs stashed as bf16
// pairs, scattered into reused xs planes, stored linearly (coalesced).
// LDS = 40 KB -> 3 blocks/CU at launch_bounds(512,6) = 24 waves/CU.
// This is the benched-best configuration (96.5 us, round 10); rounds 11-15
// established that added cross-phase register state (deeper prefetch,
// 8-waves/EU occupancy, persistent tiles, half-tile pipelining) all spill
// to scratch and regress. Do not add live state across the gather phase.
// ---------------------------------------------------------------------------
__global__ __launch_bounds__(NT, 6)
void fused_main(const float* __restrict__ x,          // [B, E]
                const float* __restrict__ llr,        // [B, NVARS]
                const uint4*  __restrict__ wtc,       // packed weight stream
                const float4* __restrict__ hdr,       // 2 x float4 per item
                const int*    __restrict__ nitems,
                float* __restrict__ out)
{
    __shared__ uint4 xs[E];        // stage: packed x; later: 4 output planes
    __shared__ uint4 ls[NVARS];

    const int b0 = blockIdx.x * TB;
    const int t  = threadIdx.x;

    {
        const float4* xr = (const float4*)(x + (size_t)b0 * E);
        const float4 r0 = xr[0 * (E / 4) + t];
        const float4 r1 = xr[1 * (E / 4) + t];
        const float4 r2 = xr[2 * (E / 4) + t];
        const float4 r3 = xr[3 * (E / 4) + t];
        const float4 r4 = xr[4 * (E / 4) + t];
        const float4 r5 = xr[5 * (E / 4) + t];
        const float4 r6 = xr[6 * (E / 4) + t];
        const float4 r7 = xr[7 * (E / 4) + t];
        xs[4 * t + 0] = make_uint4(cvtpk(r0.x, r1.x), cvtpk(r2.x, r3.x),
                                   cvtpk(r4.x, r5.x), cvtpk(r6.x, r7.x));
        xs[4 * t + 1] = make_uint4(cvtpk(r0.y, r1.y), cvtpk(r2.y, r3.y),
                                   cvtpk(r4.y, r5.y), cvtpk(r6.y, r7.y));
        xs[4 * t + 2] = make_uint4(cvtpk(r0.z, r1.z), cvtpk(r2.z, r3.z),
                                   cvtpk(r4.z, r5.z), cvtpk(r6.z, r7.z));
        xs[4 * t + 3] = make_uint4(cvtpk(r0.w, r1.w), cvtpk(r2.w, r3.w),
                                   cvtpk(r4.w, r5.w), cvtpk(r6.w, r7.w));
    }
    {
        const float* lr = llr + (size_t)b0 * NVARS;
        ls[t] = make_uint4(cvtpk(lr[t],             lr[NVARS + t]),
                           cvtpk(lr[2 * NVARS + t], lr[3 * NVARS + t]),
                           cvtpk(lr[4 * NVARS + t], lr[5 * NVARS + t]),
                           cvtpk(lr[6 * NVARS + t], lr[7 * NVARS + t]));
    }
    __syncthreads();

    const int nit = nitems[0];

    unsigned sst[2][4][4];
    unsigned scc[2][2];                        // packed cols {c01, c23}

    #pragma unroll
    for (int r = 0; r < 2; ++r) {
        scc[r][0] = 0xFFFFFFFFu;
        scc[r][1] = 0xFFFFFFFFu;
        const int it = r * NT + t;
        if (it < nit) {
            const float4 ha = hdr[2 * it];
            const uint4  hb = ((const uint4*)hdr)[2 * it + 1];
            const unsigned woff = hb.z;
            const int v = hb.w & 0xFFFF;
            const int d = hb.w >> 16;

            const uint4 lvq = ls[v];
            const float lf0 = bl(lvq.x), lf1 = bh(lvq.x);
            const float lf2 = bl(lvq.y), lf3 = bh(lvq.y);
            const float lf4 = bl(lvq.z), lf5 = bh(lvq.z);
            const float lf6 = bl(lvq.w), lf7 = bh(lvq.w);

            float a[4][8];
            #pragma unroll
            for (int ii = 0; ii < 4; ++ii) {
                const float sk = (ii == 0) ? ha.x : (ii == 1) ? ha.y
                               : (ii == 2) ? ha.z : ha.w;
                a[ii][0] = sk * lf0; a[ii][1] = sk * lf1;
                a[ii][2] = sk * lf2; a[ii][3] = sk * lf3;
                a[ii][4] = sk * lf4; a[ii][5] = sk * lf5;
                a[ii][6] = sk * lf6; a[ii][7] = sk * lf7;
            }

            const uint4* wp = wtc + woff;
            for (int j = 0; j < d; ++j) {
                const uint4 g = wp[j];                       // contiguous 16B
                const int   s = (int)(g.x & 0x7FFu);
                const uint4 xv = xs[s];                      // one ds_read_b128
                const float w0 = bh(g.x), w1 = bh(g.y);
                const float w2 = bh(g.z), w3 = bh(g.w);
                const float xf0 = bl(xv.x), xf1 = bh(xv.x);
                const float xf2 = bl(xv.y), xf3 = bh(xv.y);
                const float xf4 = bl(xv.z), xf5 = bh(xv.z);
                const float xf6 = bl(xv.w), xf7 = bh(xv.w);
                a[0][0] += w0 * xf0; a[0][1] += w0 * xf1;
                a[0][2] += w0 * xf2; a[0][3] += w0 * xf3;
                a[0][4] += w0 * xf4; a[0][5] += w0 * xf5;
                a[0][6] += w0 * xf6; a[0][7] += w0 * xf7;
                a[1][0] += w1 * xf0; a[1][1] += w1 * xf1;
                a[1][2] += w1 * xf2; a[1][3] += w1 * xf3;
                a[1][4] += w1 * xf4; a[1][5] += w1 * xf5;
                a[1][6] += w1 * xf6; a[1][7] += w1 * xf7;
                a[2][0] += w2 * xf0; a[2][1] += w2 * xf1;
                a[2][2] += w2 * xf2; a[2][3] += w2 * xf3;
                a[2][4] += w2 * xf4; a[2][5] += w2 * xf5;
                a[2][6] += w2 * xf6; a[2][7] += w2 * xf7;
                a[3][0] += w3 * xf0; a[3][1] += w3 * xf1;
                a[3][2] += w3 * xf2; a[3][3] += w3 * xf3;
                a[3][4] += w3 * xf4; a[3][5] += w3 * xf5;
                a[3][6] += w3 * xf6; a[3][7] += w3 * xf7;
            }

            scc[r][0] = hb.x;
            scc[r][1] = hb.y;
            #pragma unroll
            for (int ii = 0; ii < 4; ++ii) {
                sst[r][ii][0] = cvtpk(th(a[ii][0]), th(a[ii][1]));
                sst[r][ii][1] = cvtpk(th(a[ii][2]), th(a[ii][3]));
                sst[r][ii][2] = cvtpk(th(a[ii][4]), th(a[ii][5]));
                sst[r][ii][3] = cvtpk(th(a[ii][6]), th(a[ii][7]));
            }
        }
    }

    __syncthreads();                            // all gathers done: xs free
    unsigned* osp = (unsigned*)xs;              // 4 planes x E (row pairs)
    #pragma unroll
    for (int r = 0; r < 2; ++r) {
        #pragma unroll
        for (int ii = 0; ii < 4; ++ii) {
            const unsigned c = (scc[r][ii >> 1] >> ((ii & 1) * 16)) & 0xFFFFu;
            if (c != 0xFFFFu) {
                osp[0 * E + c] = sst[r][ii][0];
                osp[1 * E + c] = sst[r][ii][1];
                osp[2 * E + c] = sst[r][ii][2];
                osp[3 * E + c] = sst[r][ii][3];
            }
        }
    }
    __syncthreads();

    #pragma unroll
    for (int k = 0; k < E / NT; ++k) {
        const int e = k * NT + t;
        #pragma unroll
        for (int p = 0; p < 4; ++p) {
            const unsigned q = osp[p * E + e];  // coalesced linear
            out[(size_t)(b0 + 2 * p) * E + e]     = bl(q);
            out[(size_t)(b0 + 2 * p + 1) * E + e] = bh(q);
        }
    }
}

extern "C" void kernel_launch(void* const* d_in, const int* in_sizes, int n_in,
                              void* d_out, int out_size, void* d_ws, size_t ws_size,
                              hipStream_t stream) {
    const float* x        = (const float*)d_in[0];  // [B, E]
    const float* llr      = (const float*)d_in[1];  // [B, NVARS]
    const float* u        = (const float*)d_in[2];  // [E]
    const float* odd_w    = (const float*)d_in[3];  // [E, E]
    const float* llr_w    = (const float*)d_in[4];  // [NVARS, E]
    const float* logits   = (const float*)d_in[5];  // [E]
    // d_in[6] (o2e_mask) not needed: structure derived from skip mask.
    const float* skip_msk = (const float*)d_in[7];  // [NVARS, E]
    float* out = (float*)d_out;

    const int B = in_sizes[0] / E;                  // 16384

    // Workspace (~145 KB), 16B-aligned segments.
    char* wsb = (char*)d_ws;
    size_t off = 0;
    uint4*          wtc  = (uint4*)(wsb + off);          off += (size_t)6144 * 16;  // 98304
    float4*         hdr  = (float4*)(wsb + off);         off += (size_t)1024 * 32;  // 32768
    float*          skw  = (float*)(wsb + off);          off += (size_t)E * 4;      //  8192
    unsigned short* vsrc = (unsigned short*)(wsb + off); off += (size_t)E * 2;      //  4096
    int*            nit  = (int*)(wsb + off);            off += 16;

    k_vsrc  <<<dim3(E / 256, 32), dim3(256), 0, stream>>>(skip_msk, llr_w, vsrc, skw);
    k_pervar<<<dim3(NVARS),       dim3(64),  0, stream>>>(vsrc, skw, odd_w, u, logits,
                                                          wtc, hdr, nit);

    fused_main<<<dim3(B / TB), dim3(NT), 0, stream>>>(x, llr, wtc, hdr, nit, out);
}